// Round 1
// baseline (196.555 us; speedup 1.0000x reference)
//
#include <hip/hip_runtime.h>
#include <math.h>

// Problem shape (fixed by setup_inputs)
constexpr int B = 16, H = 384, W = 1280;
constexpr int HW = H * W;
constexpr int NPIX = B * HW;             // 7,864,320
constexpr int NVEC = NPIX / 4;           // float4 granules (W % 4 == 0, rows never straddled)
constexpr int NBLOCKS = 2048;
constexpr int NTHREADS = 256;
constexpr float EPSV = 1e-8f;

// ws float layout:
//   [0, 384): per-batch params, 24 floats each:
//       dir0 (n2c, warp cur->gen_next): M[9], kt[3]
//       dir1 (c2n, warp nxt->gen_cur):  M[9], kt[3]
//   [384, 384+NBLOCKS): per-block partial sums
constexpr int PARAMS_FLOATS = B * 24;    // 384

__device__ inline void aa_to_R(float x, float y, float z, float R[9]) {
    // Mirrors reference: theta = sqrt(t2 + 1e-12); A = sin/theta; B = (1-cos)/(t2+1e-12)
    float t2 = x * x + y * y + z * z;
    float th = sqrtf(t2 + 1e-12f);
    float A = sinf(th) / th;
    float Bc = (1.0f - cosf(th)) / (t2 + 1e-12f);
    R[0] = 1.0f + Bc * (-(y * y + z * z));
    R[1] = A * (-z) + Bc * (x * y);
    R[2] = A * ( y) + Bc * (x * z);
    R[3] = A * ( z) + Bc * (x * y);
    R[4] = 1.0f + Bc * (-(x * x + z * z));
    R[5] = A * (-x) + Bc * (y * z);
    R[6] = A * (-y) + Bc * (x * z);
    R[7] = A * ( x) + Bc * (y * z);
    R[8] = 1.0f + Bc * (-(x * x + y * y));
}

__device__ inline void mat3_mul(const float* A, const float* Bm, float* C) {
#pragma unroll
    for (int i = 0; i < 3; i++)
#pragma unroll
        for (int j = 0; j < 3; j++)
            C[i * 3 + j] = A[i * 3 + 0] * Bm[0 * 3 + j]
                         + A[i * 3 + 1] * Bm[1 * 3 + j]
                         + A[i * 3 + 2] * Bm[2 * 3 + j];
}

// T_rel = inv(T_a) @ T_b  (rigid):  R_rel = Ra^T Rb ; t_rel = Ra^T (tb - ta)
// Emits M = K @ R_rel @ Kinv (9 floats) then kt = K @ t_rel (3 floats).
__device__ inline void compute_dir(const float Ra[9], const float Rb[9],
                                   const float ta[3], const float tb[3],
                                   const float K[9], const float Ki[9],
                                   float* out) {
    float Rrel[9];
#pragma unroll
    for (int i = 0; i < 3; i++)
#pragma unroll
        for (int j = 0; j < 3; j++)
            Rrel[i * 3 + j] = Ra[0 * 3 + i] * Rb[0 * 3 + j]
                            + Ra[1 * 3 + i] * Rb[1 * 3 + j]
                            + Ra[2 * 3 + i] * Rb[2 * 3 + j];
    float dt[3] = { tb[0] - ta[0], tb[1] - ta[1], tb[2] - ta[2] };
    float trel[3];
#pragma unroll
    for (int i = 0; i < 3; i++)
        trel[i] = Ra[0 * 3 + i] * dt[0] + Ra[1 * 3 + i] * dt[1] + Ra[2 * 3 + i] * dt[2];
    float tmp[9], M[9];
    mat3_mul(Rrel, Ki, tmp);
    mat3_mul(K, tmp, M);
#pragma unroll
    for (int i = 0; i < 9; i++) out[i] = M[i];
#pragma unroll
    for (int i = 0; i < 3; i++)
        out[9 + i] = K[i * 3 + 0] * trel[0] + K[i * 3 + 1] * trel[1] + K[i * 3 + 2] * trel[2];
}

__global__ void grl_setup_kernel(const float* __restrict__ cpos, const float* __restrict__ npos,
                                 const float* __restrict__ cang, const float* __restrict__ nang,
                                 const float* __restrict__ Kmat, float* __restrict__ ws) {
    int b = threadIdx.x;
    if (b >= B) return;
    float Rc[9], Rn[9];
    aa_to_R(cang[3 * b + 0], cang[3 * b + 1], cang[3 * b + 2], Rc);
    aa_to_R(nang[3 * b + 0], nang[3 * b + 1], nang[3 * b + 2], Rn);
    float tc[3] = { cpos[3 * b + 0], cpos[3 * b + 1], cpos[3 * b + 2] };
    float tn[3] = { npos[3 * b + 0], npos[3 * b + 1], npos[3 * b + 2] };
    float K[9];
#pragma unroll
    for (int i = 0; i < 9; i++) K[i] = Kmat[i];
    float det = K[0] * (K[4] * K[8] - K[5] * K[7])
              - K[1] * (K[3] * K[8] - K[5] * K[6])
              + K[2] * (K[3] * K[7] - K[4] * K[6]);
    float id = 1.0f / det;
    float Ki[9] = {
        (K[4] * K[8] - K[5] * K[7]) * id, (K[2] * K[7] - K[1] * K[8]) * id, (K[1] * K[5] - K[2] * K[4]) * id,
        (K[5] * K[6] - K[3] * K[8]) * id, (K[0] * K[8] - K[2] * K[6]) * id, (K[2] * K[3] - K[0] * K[5]) * id,
        (K[3] * K[7] - K[4] * K[6]) * id, (K[1] * K[6] - K[0] * K[7]) * id, (K[0] * K[4] - K[1] * K[3]) * id };
    float* out = ws + b * 24;
    // dir0: T_n2c = inv(T_cur) @ T_next  (gen_next: dst = next depth, src = current depth)
    compute_dir(Rc, Rn, tc, tn, K, Ki, out);
    // dir1: T_c2n = inv(T_next) @ T_cur  (gen_cur: dst = current depth, src = next depth)
    compute_dir(Rn, Rc, tn, tc, K, Ki, out + 12);
}

__device__ inline float bilinear_tap(const float* __restrict__ img, int base,
                                     float xf, float yf, float w) {
    bool valid = (xf >= 0.0f) & (xf <= (float)(W - 1)) & (yf >= 0.0f) & (yf <= (float)(H - 1));
    int xi = (int)fminf(fmaxf(xf, 0.0f), (float)(W - 1));
    int yi = (int)fminf(fmaxf(yf, 0.0f), (float)(H - 1));
    float v = valid ? img[base + yi * W + xi] : 0.0f;
    return v * w;
}

__device__ inline float warp_sample(const float* __restrict__ img, int base,
                                    const float M[9], const float kt[3],
                                    float u, float v, float d) {
    float px = d * (M[0] * u + M[1] * v + M[2]) + kt[0];
    float py = d * (M[3] * u + M[4] * v + M[5]) + kt[1];
    float pz = d * (M[6] * u + M[7] * v + M[8]) + kt[2];
    float scale = (fabsf(pz) > EPSV) ? (1.0f / pz) : 1.0f;
    float ix = px * scale;
    float iy = py * scale;
    float x0 = floorf(ix), y0 = floorf(iy);
    float wx1 = ix - x0, wy1 = iy - y0;
    float wx0 = 1.0f - wx1, wy0 = 1.0f - wy1;
    float acc = bilinear_tap(img, base, x0,        y0,        wx0 * wy0);
    acc      += bilinear_tap(img, base, x0 + 1.0f, y0,        wx1 * wy0);
    acc      += bilinear_tap(img, base, x0,        y0 + 1.0f, wx0 * wy1);
    acc      += bilinear_tap(img, base, x0 + 1.0f, y0 + 1.0f, wx1 * wy1);
    return acc;
}

__global__ __launch_bounds__(NTHREADS) void grl_warp_loss_kernel(
        const float* __restrict__ cur, const float* __restrict__ nxt,
        const float* __restrict__ ws, float* __restrict__ partials) {
    float sum = 0.0f;
    for (int vid = blockIdx.x * blockDim.x + threadIdx.x; vid < NVEC;
         vid += gridDim.x * blockDim.x) {
        int p = vid * 4;
        int b = p / HW;
        int rem = p - b * HW;
        int h = rem / W;
        int w0 = rem - h * W;
        const float4 c4 = *(const float4*)(cur + p);
        const float4 n4 = *(const float4*)(nxt + p);
        const float* prm = ws + b * 24;
        float M0[9], kt0[3], M1[9], kt1[3];
#pragma unroll
        for (int i = 0; i < 9; i++) { M0[i] = prm[i]; M1[i] = prm[12 + i]; }
#pragma unroll
        for (int i = 0; i < 3; i++) { kt0[i] = prm[9 + i]; kt1[i] = prm[21 + i]; }
        int base = b * HW;
        float fh = (float)h;
        float cArr[4] = { c4.x, c4.y, c4.z, c4.w };
        float nArr[4] = { n4.x, n4.y, n4.z, n4.w };
#pragma unroll
        for (int j = 0; j < 4; j++) {
            float fw = (float)(w0 + j);
            // loss_next: gen_next = warp(src=cur, dst depth=nxt, T_n2c)
            float dN = nArr[j];
            sum += fabsf(warp_sample(cur, base, M0, kt0, fw, fh, dN) - dN);
            // loss_prev: gen_cur = warp(src=nxt, dst depth=cur, T_c2n)
            float dC = cArr[j];
            sum += fabsf(warp_sample(nxt, base, M1, kt1, fw, fh, dC) - dC);
        }
    }
    // deterministic block reduce: wave shuffle + LDS
#pragma unroll
    for (int off = 32; off > 0; off >>= 1) sum += __shfl_down(sum, off, 64);
    __shared__ float smem[NTHREADS / 64];
    int lane = threadIdx.x & 63, wid = threadIdx.x >> 6;
    if (lane == 0) smem[wid] = sum;
    __syncthreads();
    if (threadIdx.x == 0) {
        float t = 0.0f;
#pragma unroll
        for (int i = 0; i < NTHREADS / 64; i++) t += smem[i];
        partials[blockIdx.x] = t;
    }
}

__global__ __launch_bounds__(256) void grl_finalize_kernel(const float* __restrict__ partials,
                                                           float* __restrict__ out) {
    float sum = 0.0f;
    for (int i = threadIdx.x; i < NBLOCKS; i += 256) sum += partials[i];
#pragma unroll
    for (int off = 32; off > 0; off >>= 1) sum += __shfl_down(sum, off, 64);
    __shared__ float smem[4];
    int lane = threadIdx.x & 63, wid = threadIdx.x >> 6;
    if (lane == 0) smem[wid] = sum;
    __syncthreads();
    if (threadIdx.x == 0) {
        float t = smem[0] + smem[1] + smem[2] + smem[3];
        // (loss_prev + loss_next)/2 * REG_LAMBDA, each loss a mean over NPIX
        out[0] = t * (0.1f / (2.0f * (float)NPIX));
    }
}

extern "C" void kernel_launch(void* const* d_in, const int* in_sizes, int n_in,
                              void* d_out, int out_size, void* d_ws, size_t ws_size,
                              hipStream_t stream) {
    const float* cur  = (const float*)d_in[0];
    const float* nxt  = (const float*)d_in[1];
    const float* cpos = (const float*)d_in[2];
    const float* npos = (const float*)d_in[3];
    const float* cang = (const float*)d_in[4];
    const float* nang = (const float*)d_in[5];
    const float* Kmat = (const float*)d_in[6];
    float* ws = (float*)d_ws;
    float* partials = ws + PARAMS_FLOATS;

    grl_setup_kernel<<<1, 64, 0, stream>>>(cpos, npos, cang, nang, Kmat, ws);
    grl_warp_loss_kernel<<<NBLOCKS, NTHREADS, 0, stream>>>(cur, nxt, ws, partials);
    grl_finalize_kernel<<<1, 256, 0, stream>>>(partials, (float*)d_out);
}

// Round 2
// 181.423 us; speedup vs baseline: 1.0834x; 1.0834x over previous
//
#include <hip/hip_runtime.h>
#include <math.h>

// Problem shape (fixed by setup_inputs)
constexpr int B = 16, H = 384, W = 1280;
constexpr int HW = H * W;
constexpr int NPIX = B * HW;             // 7,864,320
constexpr int HW4 = HW / 4;              // 122,880 float4 granules per batch image
constexpr int W4 = W / 4;                // 320
constexpr int NBLOCKS = 2048;
constexpr int NTHREADS = 256;
constexpr int NXCD = 8;
constexpr int BLK_PER_XCD = NBLOCKS / NXCD;            // 256
constexpr int THR_PER_XCD = BLK_PER_XCD * NTHREADS;    // 65536
constexpr float EPSV = 1e-8f;

// ws float layout:
//   [0, 384): per-batch params, 24 floats each:
//       dir0 (n2c, warp cur->gen_next): M[9], kt[3]
//       dir1 (c2n, warp nxt->gen_cur):  M[9], kt[3]
//   [384, 384+NBLOCKS): per-block partial sums
constexpr int PARAMS_FLOATS = B * 24;    // 384

__device__ inline void aa_to_R(float x, float y, float z, float R[9]) {
    // Mirrors reference: theta = sqrt(t2 + 1e-12); A = sin/theta; B = (1-cos)/(t2+1e-12)
    float t2 = x * x + y * y + z * z;
    float th = sqrtf(t2 + 1e-12f);
    float A = sinf(th) / th;
    float Bc = (1.0f - cosf(th)) / (t2 + 1e-12f);
    R[0] = 1.0f + Bc * (-(y * y + z * z));
    R[1] = A * (-z) + Bc * (x * y);
    R[2] = A * ( y) + Bc * (x * z);
    R[3] = A * ( z) + Bc * (x * y);
    R[4] = 1.0f + Bc * (-(x * x + z * z));
    R[5] = A * (-x) + Bc * (y * z);
    R[6] = A * (-y) + Bc * (x * z);
    R[7] = A * ( x) + Bc * (y * z);
    R[8] = 1.0f + Bc * (-(x * x + y * y));
}

__device__ inline void mat3_mul(const float* A, const float* Bm, float* C) {
#pragma unroll
    for (int i = 0; i < 3; i++)
#pragma unroll
        for (int j = 0; j < 3; j++)
            C[i * 3 + j] = A[i * 3 + 0] * Bm[0 * 3 + j]
                         + A[i * 3 + 1] * Bm[1 * 3 + j]
                         + A[i * 3 + 2] * Bm[2 * 3 + j];
}

// T_rel = inv(T_a) @ T_b  (rigid):  R_rel = Ra^T Rb ; t_rel = Ra^T (tb - ta)
// Emits M = K @ R_rel @ Kinv (9 floats) then kt = K @ t_rel (3 floats).
__device__ inline void compute_dir(const float Ra[9], const float Rb[9],
                                   const float ta[3], const float tb[3],
                                   const float K[9], const float Ki[9],
                                   float* out) {
    float Rrel[9];
#pragma unroll
    for (int i = 0; i < 3; i++)
#pragma unroll
        for (int j = 0; j < 3; j++)
            Rrel[i * 3 + j] = Ra[0 * 3 + i] * Rb[0 * 3 + j]
                            + Ra[1 * 3 + i] * Rb[1 * 3 + j]
                            + Ra[2 * 3 + i] * Rb[2 * 3 + j];
    float dt[3] = { tb[0] - ta[0], tb[1] - ta[1], tb[2] - ta[2] };
    float trel[3];
#pragma unroll
    for (int i = 0; i < 3; i++)
        trel[i] = Ra[0 * 3 + i] * dt[0] + Ra[1 * 3 + i] * dt[1] + Ra[2 * 3 + i] * dt[2];
    float tmp[9], M[9];
    mat3_mul(Rrel, Ki, tmp);
    mat3_mul(K, tmp, M);
#pragma unroll
    for (int i = 0; i < 9; i++) out[i] = M[i];
#pragma unroll
    for (int i = 0; i < 3; i++)
        out[9 + i] = K[i * 3 + 0] * trel[0] + K[i * 3 + 1] * trel[1] + K[i * 3 + 2] * trel[2];
}

__global__ void grl_setup_kernel(const float* __restrict__ cpos, const float* __restrict__ npos,
                                 const float* __restrict__ cang, const float* __restrict__ nang,
                                 const float* __restrict__ Kmat, float* __restrict__ ws) {
    int b = threadIdx.x;
    if (b >= B) return;
    float Rc[9], Rn[9];
    aa_to_R(cang[3 * b + 0], cang[3 * b + 1], cang[3 * b + 2], Rc);
    aa_to_R(nang[3 * b + 0], nang[3 * b + 1], nang[3 * b + 2], Rn);
    float tc[3] = { cpos[3 * b + 0], cpos[3 * b + 1], cpos[3 * b + 2] };
    float tn[3] = { npos[3 * b + 0], npos[3 * b + 1], npos[3 * b + 2] };
    float K[9];
#pragma unroll
    for (int i = 0; i < 9; i++) K[i] = Kmat[i];
    float det = K[0] * (K[4] * K[8] - K[5] * K[7])
              - K[1] * (K[3] * K[8] - K[5] * K[6])
              + K[2] * (K[3] * K[7] - K[4] * K[6]);
    float id = 1.0f / det;
    float Ki[9] = {
        (K[4] * K[8] - K[5] * K[7]) * id, (K[2] * K[7] - K[1] * K[8]) * id, (K[1] * K[5] - K[2] * K[4]) * id,
        (K[5] * K[6] - K[3] * K[8]) * id, (K[0] * K[8] - K[2] * K[6]) * id, (K[2] * K[3] - K[0] * K[5]) * id,
        (K[3] * K[7] - K[4] * K[6]) * id, (K[1] * K[6] - K[0] * K[7]) * id, (K[0] * K[4] - K[1] * K[3]) * id };
    float* out = ws + b * 24;
    // dir0: T_n2c = inv(T_cur) @ T_next  (gen_next: dst = next depth, src = current depth)
    compute_dir(Rc, Rn, tc, tn, K, Ki, out);
    // dir1: T_c2n = inv(T_next) @ T_cur  (gen_cur: dst = current depth, src = next depth)
    compute_dir(Rn, Rc, tn, tc, K, Ki, out + 12);
}

__device__ inline float bilinear_tap(const float* __restrict__ img,
                                     float xf, float yf, float w) {
    bool valid = (xf >= 0.0f) & (xf <= (float)(W - 1)) & (yf >= 0.0f) & (yf <= (float)(H - 1));
    int xi = (int)fminf(fmaxf(xf, 0.0f), (float)(W - 1));
    int yi = (int)fminf(fmaxf(yf, 0.0f), (float)(H - 1));
    float v = valid ? img[yi * W + xi] : 0.0f;
    return v * w;
}

__device__ inline float warp_sample(const float* __restrict__ img,
                                    const float M[9], const float kt[3],
                                    float u, float v, float d) {
    float px = d * (M[0] * u + M[1] * v + M[2]) + kt[0];
    float py = d * (M[3] * u + M[4] * v + M[5]) + kt[1];
    float pz = d * (M[6] * u + M[7] * v + M[8]) + kt[2];
    float scale = (fabsf(pz) > EPSV) ? (1.0f / pz) : 1.0f;
    float ix = px * scale;
    float iy = py * scale;
    float x0 = floorf(ix), y0 = floorf(iy);
    float wx1 = ix - x0, wy1 = iy - y0;
    float wx0 = 1.0f - wx1, wy0 = 1.0f - wy1;
    float acc = bilinear_tap(img, x0,        y0,        wx0 * wy0);
    acc      += bilinear_tap(img, x0 + 1.0f, y0,        wx1 * wy0);
    acc      += bilinear_tap(img, x0,        y0 + 1.0f, wx0 * wy1);
    acc      += bilinear_tap(img, x0 + 1.0f, y0 + 1.0f, wx1 * wy1);
    return acc;
}

// Batch<->XCD pinning: XCD x (bid % 8) processes batches 2x then 2x+1.
// Working set per batch = cur[b]+nxt[b] = 3.93 MB -> fits the XCD's 4 MiB L2,
// so all 8 gather taps/pixel become L2 hits after first touch.
__global__ __launch_bounds__(NTHREADS) void grl_warp_loss_kernel(
        const float* __restrict__ cur, const float* __restrict__ nxt,
        const float* __restrict__ ws, float* __restrict__ partials) {
    int bid = blockIdx.x;
    int xcd = bid & (NXCD - 1);
    int j   = bid >> 3;                          // 0..BLK_PER_XCD-1
    int tid0 = j * NTHREADS + (int)threadIdx.x;  // 0..THR_PER_XCD-1
    float sum = 0.0f;

    for (int bb = 0; bb < 2; ++bb) {
        int b = xcd * 2 + bb;                    // block-uniform batch
        const float* __restrict__ prm = ws + b * 24;
        float M0[9], kt0[3], M1[9], kt1[3];
#pragma unroll
        for (int i = 0; i < 9; i++) { M0[i] = prm[i]; M1[i] = prm[12 + i]; }
#pragma unroll
        for (int i = 0; i < 3; i++) { kt0[i] = prm[9 + i]; kt1[i] = prm[21 + i]; }
        const float* __restrict__ curb = cur + b * HW;
        const float* __restrict__ nxtb = nxt + b * HW;

        for (int idx = tid0; idx < HW4; idx += THR_PER_XCD) {
            int h  = idx / W4;
            int w4 = idx - h * W4;
            int p  = (h * W4 + w4) * 4;          // = idx*4
            const float4 c4 = *(const float4*)(curb + p);
            const float4 n4 = *(const float4*)(nxtb + p);
            float fh = (float)h;
            float cArr[4] = { c4.x, c4.y, c4.z, c4.w };
            float nArr[4] = { n4.x, n4.y, n4.z, n4.w };
#pragma unroll
            for (int k = 0; k < 4; k++) {
                float fw = (float)(w4 * 4 + k);
                // loss_next: gen_next = warp(src=cur, dst depth=nxt, T_n2c)
                float dN = nArr[k];
                sum += fabsf(warp_sample(curb, M0, kt0, fw, fh, dN) - dN);
                // loss_prev: gen_cur = warp(src=nxt, dst depth=cur, T_c2n)
                float dC = cArr[k];
                sum += fabsf(warp_sample(nxtb, M1, kt1, fw, fh, dC) - dC);
            }
        }
    }

    // deterministic block reduce: wave shuffle + LDS
#pragma unroll
    for (int off = 32; off > 0; off >>= 1) sum += __shfl_down(sum, off, 64);
    __shared__ float smem[NTHREADS / 64];
    int lane = threadIdx.x & 63, wid = threadIdx.x >> 6;
    if (lane == 0) smem[wid] = sum;
    __syncthreads();
    if (threadIdx.x == 0) {
        float t = 0.0f;
#pragma unroll
        for (int i = 0; i < NTHREADS / 64; i++) t += smem[i];
        partials[blockIdx.x] = t;
    }
}

__global__ __launch_bounds__(256) void grl_finalize_kernel(const float* __restrict__ partials,
                                                           float* __restrict__ out) {
    float sum = 0.0f;
    for (int i = threadIdx.x; i < NBLOCKS; i += 256) sum += partials[i];
#pragma unroll
    for (int off = 32; off > 0; off >>= 1) sum += __shfl_down(sum, off, 64);
    __shared__ float smem[4];
    int lane = threadIdx.x & 63, wid = threadIdx.x >> 6;
    if (lane == 0) smem[wid] = sum;
    __syncthreads();
    if (threadIdx.x == 0) {
        float t = smem[0] + smem[1] + smem[2] + smem[3];
        // (loss_prev + loss_next)/2 * REG_LAMBDA, each loss a mean over NPIX
        out[0] = t * (0.1f / (2.0f * (float)NPIX));
    }
}

extern "C" void kernel_launch(void* const* d_in, const int* in_sizes, int n_in,
                              void* d_out, int out_size, void* d_ws, size_t ws_size,
                              hipStream_t stream) {
    const float* cur  = (const float*)d_in[0];
    const float* nxt  = (const float*)d_in[1];
    const float* cpos = (const float*)d_in[2];
    const float* npos = (const float*)d_in[3];
    const float* cang = (const float*)d_in[4];
    const float* nang = (const float*)d_in[5];
    const float* Kmat = (const float*)d_in[6];
    float* ws = (float*)d_ws;
    float* partials = ws + PARAMS_FLOATS;

    grl_setup_kernel<<<1, 64, 0, stream>>>(cpos, npos, cang, nang, Kmat, ws);
    grl_warp_loss_kernel<<<NBLOCKS, NTHREADS, 0, stream>>>(cur, nxt, ws, partials);
    grl_finalize_kernel<<<1, 256, 0, stream>>>(partials, (float*)d_out);
}

// Round 3
// 170.778 us; speedup vs baseline: 1.1509x; 1.0623x over previous
//
#include <hip/hip_runtime.h>
#include <math.h>

// Problem shape (fixed by setup_inputs)
constexpr int B = 16, H = 384, W = 1280;
constexpr int HW = H * W;
constexpr int NPIX = B * HW;             // 7,864,320
constexpr int HW4 = HW / 4;              // 122,880 float4 granules per batch image
constexpr int W4 = W / 4;                // 320
constexpr int NBLOCKS = 2048;
constexpr int NTHREADS = 256;
constexpr int NXCD = 8;
constexpr int BLK_PER_XCD = NBLOCKS / NXCD;            // 256
constexpr int THR_PER_XCD = BLK_PER_XCD * NTHREADS;    // 65536
constexpr float EPSV = 1e-8f;

// ws float layout: [0,384) per-batch params (24 floats each); [384,384+NBLOCKS) block partials
constexpr int PARAMS_FLOATS = B * 24;

__device__ inline void aa_to_R(float x, float y, float z, float R[9]) {
    float t2 = x * x + y * y + z * z;
    float th = sqrtf(t2 + 1e-12f);
    float A = sinf(th) / th;
    float Bc = (1.0f - cosf(th)) / (t2 + 1e-12f);
    R[0] = 1.0f + Bc * (-(y * y + z * z));
    R[1] = A * (-z) + Bc * (x * y);
    R[2] = A * ( y) + Bc * (x * z);
    R[3] = A * ( z) + Bc * (x * y);
    R[4] = 1.0f + Bc * (-(x * x + z * z));
    R[5] = A * (-x) + Bc * (y * z);
    R[6] = A * (-y) + Bc * (x * z);
    R[7] = A * ( x) + Bc * (y * z);
    R[8] = 1.0f + Bc * (-(x * x + y * y));
}

__device__ inline void mat3_mul(const float* A, const float* Bm, float* C) {
#pragma unroll
    for (int i = 0; i < 3; i++)
#pragma unroll
        for (int j = 0; j < 3; j++)
            C[i * 3 + j] = A[i * 3 + 0] * Bm[0 * 3 + j]
                         + A[i * 3 + 1] * Bm[1 * 3 + j]
                         + A[i * 3 + 2] * Bm[2 * 3 + j];
}

__device__ inline void compute_dir(const float Ra[9], const float Rb[9],
                                   const float ta[3], const float tb[3],
                                   const float K[9], const float Ki[9],
                                   float* out) {
    float Rrel[9];
#pragma unroll
    for (int i = 0; i < 3; i++)
#pragma unroll
        for (int j = 0; j < 3; j++)
            Rrel[i * 3 + j] = Ra[0 * 3 + i] * Rb[0 * 3 + j]
                            + Ra[1 * 3 + i] * Rb[1 * 3 + j]
                            + Ra[2 * 3 + i] * Rb[2 * 3 + j];
    float dt[3] = { tb[0] - ta[0], tb[1] - ta[1], tb[2] - ta[2] };
    float trel[3];
#pragma unroll
    for (int i = 0; i < 3; i++)
        trel[i] = Ra[0 * 3 + i] * dt[0] + Ra[1 * 3 + i] * dt[1] + Ra[2 * 3 + i] * dt[2];
    float tmp[9], M[9];
    mat3_mul(Rrel, Ki, tmp);
    mat3_mul(K, tmp, M);
#pragma unroll
    for (int i = 0; i < 9; i++) out[i] = M[i];
#pragma unroll
    for (int i = 0; i < 3; i++)
        out[9 + i] = K[i * 3 + 0] * trel[0] + K[i * 3 + 1] * trel[1] + K[i * 3 + 2] * trel[2];
}

__global__ void grl_setup_kernel(const float* __restrict__ cpos, const float* __restrict__ npos,
                                 const float* __restrict__ cang, const float* __restrict__ nang,
                                 const float* __restrict__ Kmat, float* __restrict__ ws) {
    int b = threadIdx.x;
    if (b >= B) return;
    float Rc[9], Rn[9];
    aa_to_R(cang[3 * b + 0], cang[3 * b + 1], cang[3 * b + 2], Rc);
    aa_to_R(nang[3 * b + 0], nang[3 * b + 1], nang[3 * b + 2], Rn);
    float tc[3] = { cpos[3 * b + 0], cpos[3 * b + 1], cpos[3 * b + 2] };
    float tn[3] = { npos[3 * b + 0], npos[3 * b + 1], npos[3 * b + 2] };
    float K[9];
#pragma unroll
    for (int i = 0; i < 9; i++) K[i] = Kmat[i];
    float det = K[0] * (K[4] * K[8] - K[5] * K[7])
              - K[1] * (K[3] * K[8] - K[5] * K[6])
              + K[2] * (K[3] * K[7] - K[4] * K[6]);
    float id = 1.0f / det;
    float Ki[9] = {
        (K[4] * K[8] - K[5] * K[7]) * id, (K[2] * K[7] - K[1] * K[8]) * id, (K[1] * K[5] - K[2] * K[4]) * id,
        (K[5] * K[6] - K[3] * K[8]) * id, (K[0] * K[8] - K[2] * K[6]) * id, (K[2] * K[3] - K[0] * K[5]) * id,
        (K[3] * K[7] - K[4] * K[6]) * id, (K[1] * K[6] - K[0] * K[7]) * id, (K[0] * K[4] - K[1] * K[3]) * id };
    float* out = ws + b * 24;
    compute_dir(Rc, Rn, tc, tn, K, Ki, out);        // dir0: T_n2c
    compute_dir(Rn, Rc, tn, tc, K, Ki, out + 12);   // dir1: T_c2n
}

// Batch<->XCD pinning (R1, kept): per-batch 3.9 MB working set fits one XCD's 4 MiB L2.
// R2: max gather ILP — compute all 32 tap offsets/weights, then issue all 32
// predicated loads back-to-back, then accumulate. __launch_bounds__(256,4)
// raises the VGPR cap to 128 so the loads can actually stay in flight.
__global__ __launch_bounds__(NTHREADS, 4) void grl_warp_loss_kernel(
        const float* __restrict__ cur, const float* __restrict__ nxt,
        const float* __restrict__ ws, float* __restrict__ partials) {
    int bid = blockIdx.x;
    int xcd = bid & (NXCD - 1);
    int j   = bid >> 3;
    int tid0 = j * NTHREADS + (int)threadIdx.x;
    float sum = 0.0f;

    for (int bb = 0; bb < 2; ++bb) {
        int b = xcd * 2 + bb;
        const float* __restrict__ prm = ws + b * 24;
        float M[2][9], kt[2][3];
#pragma unroll
        for (int i = 0; i < 9; i++) { M[0][i] = prm[i]; M[1][i] = prm[12 + i]; }
#pragma unroll
        for (int i = 0; i < 3; i++) { kt[0][i] = prm[9 + i]; kt[1][i] = prm[21 + i]; }
        const float* __restrict__ srcimg[2];
        srcimg[0] = cur + b * HW;   // dir0 samples cur
        srcimg[1] = nxt + b * HW;   // dir1 samples nxt

        for (int idx = tid0; idx < HW4; idx += THR_PER_XCD) {
            int h  = idx / W4;
            int w4 = idx - h * W4;
            int p  = idx * 4;
            const float4 c4 = *(const float4*)(srcimg[0] + p);
            const float4 n4 = *(const float4*)(srcimg[1] + p);
            float fh = (float)h;
            // dir0 warps with dst depth = next; dir1 with dst depth = current
            float dst[2][4] = { { n4.x, n4.y, n4.z, n4.w },
                                { c4.x, c4.y, c4.z, c4.w } };

            int   off[2][4][4];
            float wgt[2][4][4];
            bool  vld[2][4][4];
#pragma unroll
            for (int dir = 0; dir < 2; dir++) {
                // per-row hoisted: M1*v + M2
                float rx = M[dir][1] * fh + M[dir][2];
                float ry = M[dir][4] * fh + M[dir][5];
                float rz = M[dir][7] * fh + M[dir][8];
#pragma unroll
                for (int k = 0; k < 4; k++) {
                    float fw = (float)(w4 * 4 + k);
                    float d  = dst[dir][k];
                    float px = d * (M[dir][0] * fw + rx) + kt[dir][0];
                    float py = d * (M[dir][3] * fw + ry) + kt[dir][1];
                    float pz = d * (M[dir][6] * fw + rz) + kt[dir][2];
                    float scale = (fabsf(pz) > EPSV) ? (1.0f / pz) : 1.0f;
                    float ix = px * scale, iy = py * scale;
                    float x0 = floorf(ix), y0 = floorf(iy);
                    float wx1 = ix - x0, wy1 = iy - y0;
                    float wx0 = 1.0f - wx1, wy0 = 1.0f - wy1;
                    float ww[4] = { wx0 * wy0, wx1 * wy0, wx0 * wy1, wx1 * wy1 };
#pragma unroll
                    for (int t = 0; t < 4; t++) {
                        float xf = x0 + (float)(t & 1);
                        float yf = y0 + (float)(t >> 1);
                        bool v = (xf >= 0.0f) & (xf <= (float)(W - 1)) &
                                 (yf >= 0.0f) & (yf <= (float)(H - 1));
                        int xi = (int)fminf(fmaxf(xf, 0.0f), (float)(W - 1));
                        int yi = (int)fminf(fmaxf(yf, 0.0f), (float)(H - 1));
                        off[dir][k][t] = yi * W + xi;
                        wgt[dir][k][t] = ww[t];
                        vld[dir][k][t] = v;
                    }
                }
            }
            // Issue all 32 predicated gathers (independent -> scheduler clusters them)
            float val[2][4][4];
#pragma unroll
            for (int dir = 0; dir < 2; dir++)
#pragma unroll
                for (int k = 0; k < 4; k++)
#pragma unroll
                    for (int t = 0; t < 4; t++)
                        val[dir][k][t] = vld[dir][k][t] ? srcimg[dir][off[dir][k][t]] : 0.0f;
#pragma unroll
            for (int dir = 0; dir < 2; dir++)
#pragma unroll
                for (int k = 0; k < 4; k++) {
                    float acc = val[dir][k][0] * wgt[dir][k][0]
                              + val[dir][k][1] * wgt[dir][k][1]
                              + val[dir][k][2] * wgt[dir][k][2]
                              + val[dir][k][3] * wgt[dir][k][3];
                    sum += fabsf(acc - dst[dir][k]);
                }
        }
    }

#pragma unroll
    for (int off2 = 32; off2 > 0; off2 >>= 1) sum += __shfl_down(sum, off2, 64);
    __shared__ float smem[NTHREADS / 64];
    int lane = threadIdx.x & 63, wid = threadIdx.x >> 6;
    if (lane == 0) smem[wid] = sum;
    __syncthreads();
    if (threadIdx.x == 0) {
        float t = 0.0f;
#pragma unroll
        for (int i = 0; i < NTHREADS / 64; i++) t += smem[i];
        partials[blockIdx.x] = t;
    }
}

__global__ __launch_bounds__(256) void grl_finalize_kernel(const float* __restrict__ partials,
                                                           float* __restrict__ out) {
    float sum = 0.0f;
    for (int i = threadIdx.x; i < NBLOCKS; i += 256) sum += partials[i];
#pragma unroll
    for (int off = 32; off > 0; off >>= 1) sum += __shfl_down(sum, off, 64);
    __shared__ float smem[4];
    int lane = threadIdx.x & 63, wid = threadIdx.x >> 6;
    if (lane == 0) smem[wid] = sum;
    __syncthreads();
    if (threadIdx.x == 0) {
        float t = smem[0] + smem[1] + smem[2] + smem[3];
        out[0] = t * (0.1f / (2.0f * (float)NPIX));
    }
}

extern "C" void kernel_launch(void* const* d_in, const int* in_sizes, int n_in,
                              void* d_out, int out_size, void* d_ws, size_t ws_size,
                              hipStream_t stream) {
    const float* cur  = (const float*)d_in[0];
    const float* nxt  = (const float*)d_in[1];
    const float* cpos = (const float*)d_in[2];
    const float* npos = (const float*)d_in[3];
    const float* cang = (const float*)d_in[4];
    const float* nang = (const float*)d_in[5];
    const float* Kmat = (const float*)d_in[6];
    float* ws = (float*)d_ws;
    float* partials = ws + PARAMS_FLOATS;

    grl_setup_kernel<<<1, 64, 0, stream>>>(cpos, npos, cang, nang, Kmat, ws);
    grl_warp_loss_kernel<<<NBLOCKS, NTHREADS, 0, stream>>>(cur, nxt, ws, partials);
    grl_finalize_kernel<<<1, 256, 0, stream>>>(partials, (float*)d_out);
}

// Round 4
// 116.923 us; speedup vs baseline: 1.6811x; 1.4606x over previous
//
#include <hip/hip_runtime.h>
#include <math.h>

// Problem shape (fixed by setup_inputs)
constexpr int B = 16, H = 384, W = 1280;
constexpr int HW = H * W;
constexpr int NPIX = B * HW;             // 7,864,320
constexpr int HW4 = HW / 4;              // 122,880 float4 granules per batch image
constexpr int W4 = W / 4;                // 320
constexpr int NBLOCKS = 2048;
constexpr int NTHREADS = 256;
constexpr int NXCD = 8;
constexpr int BLK_PER_XCD = NBLOCKS / NXCD;            // 256
constexpr int THR_PER_XCD = BLK_PER_XCD * NTHREADS;    // 65536
constexpr float EPSV = 1e-8f;

// ws float layout: [0,384) per-batch params (24 floats each); [384,384+NBLOCKS) block partials
constexpr int PARAMS_FLOATS = B * 24;

__device__ inline void aa_to_R(float x, float y, float z, float R[9]) {
    float t2 = x * x + y * y + z * z;
    float th = sqrtf(t2 + 1e-12f);
    float A = sinf(th) / th;
    float Bc = (1.0f - cosf(th)) / (t2 + 1e-12f);
    R[0] = 1.0f + Bc * (-(y * y + z * z));
    R[1] = A * (-z) + Bc * (x * y);
    R[2] = A * ( y) + Bc * (x * z);
    R[3] = A * ( z) + Bc * (x * y);
    R[4] = 1.0f + Bc * (-(x * x + z * z));
    R[5] = A * (-x) + Bc * (y * z);
    R[6] = A * (-y) + Bc * (x * z);
    R[7] = A * ( x) + Bc * (y * z);
    R[8] = 1.0f + Bc * (-(x * x + y * y));
}

__device__ inline void mat3_mul(const float* A, const float* Bm, float* C) {
#pragma unroll
    for (int i = 0; i < 3; i++)
#pragma unroll
        for (int j = 0; j < 3; j++)
            C[i * 3 + j] = A[i * 3 + 0] * Bm[0 * 3 + j]
                         + A[i * 3 + 1] * Bm[1 * 3 + j]
                         + A[i * 3 + 2] * Bm[2 * 3 + j];
}

__device__ inline void compute_dir(const float Ra[9], const float Rb[9],
                                   const float ta[3], const float tb[3],
                                   const float K[9], const float Ki[9],
                                   float* out) {
    float Rrel[9];
#pragma unroll
    for (int i = 0; i < 3; i++)
#pragma unroll
        for (int j = 0; j < 3; j++)
            Rrel[i * 3 + j] = Ra[0 * 3 + i] * Rb[0 * 3 + j]
                            + Ra[1 * 3 + i] * Rb[1 * 3 + j]
                            + Ra[2 * 3 + i] * Rb[2 * 3 + j];
    float dt[3] = { tb[0] - ta[0], tb[1] - ta[1], tb[2] - ta[2] };
    float trel[3];
#pragma unroll
    for (int i = 0; i < 3; i++)
        trel[i] = Ra[0 * 3 + i] * dt[0] + Ra[1 * 3 + i] * dt[1] + Ra[2 * 3 + i] * dt[2];
    float tmp[9], M[9];
    mat3_mul(Rrel, Ki, tmp);
    mat3_mul(K, tmp, M);
#pragma unroll
    for (int i = 0; i < 9; i++) out[i] = M[i];
#pragma unroll
    for (int i = 0; i < 3; i++)
        out[9 + i] = K[i * 3 + 0] * trel[0] + K[i * 3 + 1] * trel[1] + K[i * 3 + 2] * trel[2];
}

__global__ void grl_setup_kernel(const float* __restrict__ cpos, const float* __restrict__ npos,
                                 const float* __restrict__ cang, const float* __restrict__ nang,
                                 const float* __restrict__ Kmat, float* __restrict__ ws) {
    int b = threadIdx.x;
    if (b >= B) return;
    float Rc[9], Rn[9];
    aa_to_R(cang[3 * b + 0], cang[3 * b + 1], cang[3 * b + 2], Rc);
    aa_to_R(nang[3 * b + 0], nang[3 * b + 1], nang[3 * b + 2], Rn);
    float tc[3] = { cpos[3 * b + 0], cpos[3 * b + 1], cpos[3 * b + 2] };
    float tn[3] = { npos[3 * b + 0], npos[3 * b + 1], npos[3 * b + 2] };
    float K[9];
#pragma unroll
    for (int i = 0; i < 9; i++) K[i] = Kmat[i];
    float det = K[0] * (K[4] * K[8] - K[5] * K[7])
              - K[1] * (K[3] * K[8] - K[5] * K[6])
              + K[2] * (K[3] * K[7] - K[4] * K[6]);
    float id = 1.0f / det;
    float Ki[9] = {
        (K[4] * K[8] - K[5] * K[7]) * id, (K[2] * K[7] - K[1] * K[8]) * id, (K[1] * K[5] - K[2] * K[4]) * id,
        (K[5] * K[6] - K[3] * K[8]) * id, (K[0] * K[8] - K[2] * K[6]) * id, (K[2] * K[3] - K[0] * K[5]) * id,
        (K[3] * K[7] - K[4] * K[6]) * id, (K[1] * K[6] - K[0] * K[7]) * id, (K[0] * K[4] - K[1] * K[3]) * id };
    float* out = ws + b * 24;
    compute_dir(Rc, Rn, tc, tn, K, Ki, out);        // dir0: T_n2c
    compute_dir(Rn, Rc, tn, tc, K, Ki, out + 12);   // dir1: T_c2n
}

// 8-byte pair load at 4B alignment; compiler picks the legal lowering
// (dwordx2 if gfx950 allows align-4, else 2x dword — never worse than before).
__device__ inline float2 load2u(const float* __restrict__ p) {
    float2 v;
    __builtin_memcpy(&v, p, sizeof(float2));
    return v;
}

// R1: batch<->XCD pinning (3.9 MB/batch fits an XCD's 4 MiB L2).
// R3: (a) bilinear x-pair as ONE 8B load  -> 16 loads/iter instead of 32;
//     (b) sched_barrier(0) between load cluster and consume cluster so the
//         compiler cannot sink loads to uses (R2 failure mode: VGPR stayed 44).
__global__ __launch_bounds__(NTHREADS, 4) void grl_warp_loss_kernel(
        const float* __restrict__ cur, const float* __restrict__ nxt,
        const float* __restrict__ ws, float* __restrict__ partials) {
    int bid = blockIdx.x;
    int xcd = bid & (NXCD - 1);
    int j   = bid >> 3;
    int tid0 = j * NTHREADS + (int)threadIdx.x;
    float sum = 0.0f;

    for (int bb = 0; bb < 2; ++bb) {
        int b = xcd * 2 + bb;
        const float* __restrict__ prm = ws + b * 24;
        float M[2][9], kt[2][3];
#pragma unroll
        for (int i = 0; i < 9; i++) { M[0][i] = prm[i]; M[1][i] = prm[12 + i]; }
#pragma unroll
        for (int i = 0; i < 3; i++) { kt[0][i] = prm[9 + i]; kt[1][i] = prm[21 + i]; }
        const float* __restrict__ srcimg[2];
        srcimg[0] = cur + b * HW;   // dir0 samples cur
        srcimg[1] = nxt + b * HW;   // dir1 samples nxt

        for (int idx = tid0; idx < HW4; idx += THR_PER_XCD) {
            int h  = idx / W4;
            int w4 = idx - h * W4;
            int p  = idx * 4;
            const float4 c4 = *(const float4*)(srcimg[0] + p);
            const float4 n4 = *(const float4*)(srcimg[1] + p);
            float fh = (float)h;
            // dir0 warps with dst depth = next; dir1 with dst depth = current
            float dst[2][4] = { { n4.x, n4.y, n4.z, n4.w },
                                { c4.x, c4.y, c4.z, c4.w } };

            float2 pv[2][4][2];              // [dir][k][row] pair values
            float  mxl[2][4], mxr[2][4];     // x-weights * x-validity
            float  myt[2][4], myb[2][4];     // y-weights * y-validity
            int    sL[2][4], sR[2][4];       // 0/1 selects within pair

#pragma unroll
            for (int dir = 0; dir < 2; dir++) {
                float rx = M[dir][1] * fh + M[dir][2];
                float ry = M[dir][4] * fh + M[dir][5];
                float rz = M[dir][7] * fh + M[dir][8];
#pragma unroll
                for (int k = 0; k < 4; k++) {
                    float fw = (float)(w4 * 4 + k);
                    float d  = dst[dir][k];
                    float px = d * (M[dir][0] * fw + rx) + kt[dir][0];
                    float py = d * (M[dir][3] * fw + ry) + kt[dir][1];
                    float pz = d * (M[dir][6] * fw + rz) + kt[dir][2];
                    float scale = (fabsf(pz) > EPSV) ? (1.0f / pz) : 1.0f;
                    float ix = px * scale, iy = py * scale;
                    float x0f = floorf(ix), y0f = floorf(iy);
                    float wx1 = ix - x0f, wy1 = iy - y0f;
                    float wx0 = 1.0f - wx1, wy0 = 1.0f - wy1;
                    // validity on UNclamped tap coords (matches reference)
                    bool vx0 = (x0f >= 0.0f)        & (x0f <= (float)(W - 1));
                    bool vx1 = (x0f + 1.0f >= 0.0f) & (x0f + 1.0f <= (float)(W - 1));
                    bool vy0 = (y0f >= 0.0f)        & (y0f <= (float)(H - 1));
                    bool vy1 = (y0f + 1.0f >= 0.0f) & (y0f + 1.0f <= (float)(H - 1));
                    mxl[dir][k] = vx0 ? wx0 : 0.0f;
                    mxr[dir][k] = vx1 ? wx1 : 0.0f;
                    myt[dir][k] = vy0 ? wy0 : 0.0f;
                    myb[dir][k] = vy1 ? wy1 : 0.0f;
                    int xi0 = (int)fminf(fmaxf(x0f,        0.0f), (float)(W - 1));
                    int xi1 = (int)fminf(fmaxf(x0f + 1.0f, 0.0f), (float)(W - 1));
                    int yi0 = (int)fminf(fmaxf(y0f,        0.0f), (float)(H - 1));
                    int yi1 = (int)fminf(fmaxf(y0f + 1.0f, 0.0f), (float)(H - 1));
                    int xp  = min(xi0, W - 2);       // pair base, always in-bounds
                    sL[dir][k] = xi0 - xp;           // 0 or 1
                    sR[dir][k] = xi1 - xp;           // 0 or 1
                    pv[dir][k][0] = load2u(srcimg[dir] + yi0 * W + xp);
                    pv[dir][k][1] = load2u(srcimg[dir] + yi1 * W + xp);
                }
            }
            // Keep all 16 pair-loads in flight; compiler may not sink them below.
            __builtin_amdgcn_sched_barrier(0);
#pragma unroll
            for (int dir = 0; dir < 2; dir++)
#pragma unroll
                for (int k = 0; k < 4; k++) {
                    float2 p0 = pv[dir][k][0], p1 = pv[dir][k][1];
                    float v00 = sL[dir][k] ? p0.y : p0.x;
                    float v01 = sR[dir][k] ? p0.y : p0.x;
                    float v10 = sL[dir][k] ? p1.y : p1.x;
                    float v11 = sR[dir][k] ? p1.y : p1.x;
                    float acc = (v00 * mxl[dir][k] + v01 * mxr[dir][k]) * myt[dir][k]
                              + (v10 * mxl[dir][k] + v11 * mxr[dir][k]) * myb[dir][k];
                    sum += fabsf(acc - dst[dir][k]);
                }
        }
    }

#pragma unroll
    for (int off2 = 32; off2 > 0; off2 >>= 1) sum += __shfl_down(sum, off2, 64);
    __shared__ float smem[NTHREADS / 64];
    int lane = threadIdx.x & 63, wid = threadIdx.x >> 6;
    if (lane == 0) smem[wid] = sum;
    __syncthreads();
    if (threadIdx.x == 0) {
        float t = 0.0f;
#pragma unroll
        for (int i = 0; i < NTHREADS / 64; i++) t += smem[i];
        partials[blockIdx.x] = t;
    }
}

__global__ __launch_bounds__(256) void grl_finalize_kernel(const float* __restrict__ partials,
                                                           float* __restrict__ out) {
    float sum = 0.0f;
    for (int i = threadIdx.x; i < NBLOCKS; i += 256) sum += partials[i];
#pragma unroll
    for (int off = 32; off > 0; off >>= 1) sum += __shfl_down(sum, off, 64);
    __shared__ float smem[4];
    int lane = threadIdx.x & 63, wid = threadIdx.x >> 6;
    if (lane == 0) smem[wid] = sum;
    __syncthreads();
    if (threadIdx.x == 0) {
        float t = smem[0] + smem[1] + smem[2] + smem[3];
        out[0] = t * (0.1f / (2.0f * (float)NPIX));
    }
}

extern "C" void kernel_launch(void* const* d_in, const int* in_sizes, int n_in,
                              void* d_out, int out_size, void* d_ws, size_t ws_size,
                              hipStream_t stream) {
    const float* cur  = (const float*)d_in[0];
    const float* nxt  = (const float*)d_in[1];
    const float* cpos = (const float*)d_in[2];
    const float* npos = (const float*)d_in[3];
    const float* cang = (const float*)d_in[4];
    const float* nang = (const float*)d_in[5];
    const float* Kmat = (const float*)d_in[6];
    float* ws = (float*)d_ws;
    float* partials = ws + PARAMS_FLOATS;

    grl_setup_kernel<<<1, 64, 0, stream>>>(cpos, npos, cang, nang, Kmat, ws);
    grl_warp_loss_kernel<<<NBLOCKS, NTHREADS, 0, stream>>>(cur, nxt, ws, partials);
    grl_finalize_kernel<<<1, 256, 0, stream>>>(partials, (float*)d_out);
}